// Round 16
// baseline (189.582 us; speedup 1.0000x reference)
//
#include <hip/hip_runtime.h>
#include <stdint.h>

#define PI_F 3.14159265358979323846f

// complex helpers (float2 = {re, im})
__device__ __forceinline__ float2 cmul(float2 a, float2 b) {
    return make_float2(fmaf(a.x, b.x, -a.y * b.y),
                       fmaf(a.x, b.y,  a.y * b.x));
}
__device__ __forceinline__ float2 cfma(float2 a, float2 b, float2 c) { // a*b + c
    return make_float2(fmaf(a.x, b.x, fmaf(-a.y, b.y, c.x)),
                       fmaf(a.x, b.y, fmaf( a.y, b.x, c.y)));
}

// bf16 pair pack: low 16 = re, high 16 = im (RNE)
__device__ __forceinline__ uint32_t pack_c(float2 v) {
    uint32_t a = __float_as_uint(v.x), b = __float_as_uint(v.y);
    a = (a + 0x7FFFu + ((a >> 16) & 1u)) >> 16;
    b = (b + 0x7FFFu + ((b >> 16) & 1u)) >> 16;
    return a | (b << 16);
}
// FINAL output pack: low 16 = IM, high 16 = RE (validated output convention)
__device__ __forceinline__ uint32_t pack_fin(float2 v) {
    uint32_t a = __float_as_uint(v.x), b = __float_as_uint(v.y);
    a = (a + 0x7FFFu + ((a >> 16) & 1u)) >> 16;
    b = (b + 0x7FFFu + ((b >> 16) & 1u)) >> 16;
    return b | (a << 16);
}
__device__ __forceinline__ float2 unpack_c(uint32_t u) {
    return make_float2(__uint_as_float(u << 16), __uint_as_float(u & 0xFFFF0000u));
}

__device__ __forceinline__ int g5(int v)  { return (v ^ (v >> 1)) & 31; }
__device__ __forceinline__ int ig5(int v) { v ^= v >> 1; v ^= v >> 2; v ^= v >> 4; return v & 31; }
__device__ __forceinline__ int ig6(int v) { v ^= v >> 1; v ^= v >> 2; v ^= v >> 4; return v & 63; }

// gate-table access: sU[w*8 + (2*row+col)*2]
#define LDC(w, idx) make_float2(sU[(w)*8 + (idx)*2], sU[(w)*8 + (idx)*2 + 1])
#define FCOL(w, beta) make_float2(sU[(w)*8 + (beta)*4], sU[(w)*8 + (beta)*4 + 1])

// per-block gate table: U_w = RX(p1)·RZ(p0)·RY(pi*x_bw), 16 wires x 8 floats
__device__ __forceinline__ void build_table(float* sU, const float* __restrict__ x,
                                            const float* __restrict__ par, int batch, int tid) {
    if (tid < 16) {
        const int w = tid;
        float sy, cy, sz, cz, sx, cx;
        sincosf(0.5f * PI_F * x[batch * 16 + w], &sy, &cy);
        sincosf(0.5f * par[w * 2 + 0], &sz, &cz);
        sincosf(0.5f * par[w * 2 + 1], &sx, &cx);
        float ccc = cx * cy * cz, sss = sx * sy * sz;
        float ccs = cx * cy * sz, ssc = sx * sy * cz;
        float csc = cx * sy * cz, scs = sx * cy * sz;
        float css = cx * sy * sz, scc = sx * cy * cz;
        float* o = sU + w * 8;
        o[0] = ccc + sss;  o[1] = -(ccs + ssc);   // u00
        o[2] = scs - csc;  o[3] = css - scc;      // u01
        o[4] = csc - scs;  o[5] = css - scc;      // u10
        o[6] = ccc + sss;  o[7] = ccs + ssc;      // u11
    }
    __syncthreads();
}

// gates on slab bits 0..10, transposed ownership e = (r<<6)|lane.
// bits 0..5 = lane bits (shuffles, wires 15..10); bits 6..10 = register bits (wires 9..5)
__device__ __forceinline__ void apply11_T(float2 (&A)[32], const float* __restrict__ sU, int lane) {
    #pragma unroll
    for (int p = 0; p <= 5; ++p) {
        const int w = 15 - p;
        float2 u00 = LDC(w, 0), u01 = LDC(w, 1), u10 = LDC(w, 2), u11 = LDC(w, 3);
        const int myb = (lane >> p) & 1;
        float2 ca = myb ? u11 : u00;
        float2 cb = myb ? u10 : u01;
        #pragma unroll
        for (int r = 0; r < 32; ++r) {
            float px = __shfl_xor(A[r].x, 1 << p, 64);
            float py = __shfl_xor(A[r].y, 1 << p, 64);
            A[r] = cfma(cb, make_float2(px, py), cmul(ca, A[r]));
        }
    }
    #pragma unroll
    for (int k = 0; k <= 4; ++k) {                   // slab bit 6+k, wire 9-k
        const int w = 9 - k;
        float2 u00 = LDC(w, 0), u01 = LDC(w, 1), u10 = LDC(w, 2), u11 = LDC(w, 3);
        const int m = 1 << k;
        #pragma unroll
        for (int g = 0; g < 16; ++g) {
            int i = ((g >> k) << (k + 1)) | (g & (m - 1));
            int j = i | m;
            float2 a = A[i], b = A[j];
            A[i] = cfma(u01, b, cmul(u00, a));
            A[j] = cfma(u11, b, cmul(u10, a));
        }
    }
}

// ---- Fused kernel: one block (1024 thr) = one batch; state in registers; LDS re-chunk.
// LDS (128KB) caps residency at 1 block/CU = 4 waves/EU; pin the register budget to match
// (512/4 = 128 VGPR) so the compiler does NOT target 8 waves/EU and spill (R15: 400MB scratch).
__global__ __launch_bounds__(1024) __attribute__((amdgpu_waves_per_eu(4, 4)))
void k_fused(const float* __restrict__ x,
             const float* __restrict__ par,
             uint32_t* __restrict__ out) {
    __shared__ float sU[128];
    __shared__ uint32_t ex[32768];     // 128 KB staging: 16 slabs x 2048
    const int tid = threadIdx.x, lane = tid & 63, wv = tid >> 6;   // 16 waves
    const int batch = blockIdx.x;
    build_table(sU, x, par, batch, tid);

    uint32_t P[2][32];   // phase-B state: P[d][t], bf16-packed

    // ======== Phase A (gen + layer-2 low gates) + A->B exchange, 2 halves ========
    #pragma unroll
    for (int step = 0; step < 2; ++step) {
        const int chunk = wv | (step << 4);           // slab = s bits 11..15
        const int gc = chunk ^ (chunk >> 1);
        float2 com = make_float2(1.f, 0.f);
        #pragma unroll
        for (int p = 11; p <= 15; ++p)
            com = cmul(com, FCOL(15 - p, (gc >> (p - 11)) & 1));
        #pragma unroll
        for (int p = 0; p <= 4; ++p)
            com = cmul(com, FCOL(15 - p, ((lane >> p) ^ (lane >> (p + 1))) & 1));
        const int l5 = (lane >> 5) & 1;
        const int c0 = chunk & 1;
        const float2 fa10 = FCOL(10, l5), fb10 = FCOL(10, l5 ^ 1);   // p=5:  l5 ^ r0
        const float2 fa9  = FCOL(9, 0),   fb9  = FCOL(9, 1);         // p=6:  r0 ^ r1
        const float2 fa8  = FCOL(8, 0),   fb8  = FCOL(8, 1);         // p=7:  r1 ^ r2
        const float2 fa7  = FCOL(7, 0),   fb7  = FCOL(7, 1);         // p=8:  r2 ^ r3
        const float2 fa6  = FCOL(6, 0),   fb6  = FCOL(6, 1);         // p=9:  r3 ^ r4
        const float2 fa5  = FCOL(5, c0),  fb5  = FCOL(5, c0 ^ 1);    // p=10: r4 ^ c0
        float2 A[32];
        #pragma unroll
        for (int r = 0; r < 32; ++r) {
            float2 v = com;
            v = cmul(v, ((r & 1) != 0)                     ? fb10 : fa10);
            v = cmul(v, ((((r >> 0) ^ (r >> 1)) & 1) != 0) ? fb9 : fa9);
            v = cmul(v, ((((r >> 1) ^ (r >> 2)) & 1) != 0) ? fb8 : fa8);
            v = cmul(v, ((((r >> 2) ^ (r >> 3)) & 1) != 0) ? fb7 : fa7);
            v = cmul(v, ((((r >> 3) ^ (r >> 4)) & 1) != 0) ? fb6 : fa6);
            v = cmul(v, (((r >> 4) & 1) != 0)              ? fb5 : fa5);
            A[r] = v;
        }
        apply11_T(A, sU, lane);                        // layer-2, wires 15..5
        {   // write slab to LDS at ig11-permuted position (validated store map)
            uint32_t* lb = ex + ((chunk & 15) << 11);
            const int igl = ig6(lane);
            #pragma unroll
            for (int r = 0; r < 32; ++r)
                lb[(ig5(r) << 6) | (igl ^ ((__popc(r) & 1) ? 63 : 0))] = pack_c(A[r]);
        }
        __syncthreads();
        // read phase-B share for t in this half (validated p2 read map, y = tid)
        #pragma unroll
        for (int tt = 0; tt < 16; ++tt) {
            #pragma unroll
            for (int d = 0; d < 2; ++d)
                P[d][(step << 4) | tt] =
                    ex[(tt << 11) | (d << 10) | (tid ^ (d ? 1023 : 0))];
        }
        __syncthreads();
    }

    // ======== Phase B: layer-2 high, CNOT relabel, layer-3 high ========
    // layer-2 (s-bits 11..15): d-containers independent -> f32 per container
    #pragma unroll
    for (int d = 0; d < 2; ++d) {
        float2 B[32];
        #pragma unroll
        for (int t = 0; t < 32; ++t) B[t] = unpack_c(P[d][t]);
        #pragma unroll
        for (int j = 0; j < 5; ++j) {
            const int w = 4 - j, m = 1 << j;
            float2 u00 = LDC(w, 0), u01 = LDC(w, 1), u10 = LDC(w, 2), u11 = LDC(w, 3);
            #pragma unroll
            for (int g = 0; g < 16; ++g) {
                const int t0 = ((g >> j) << (j + 1)) | (g & (m - 1));
                const int t1 = t0 | m;
                float2 a = B[t0], b = B[t1];
                B[t0] = cfma(u01, b, cmul(u00, a));
                B[t1] = cfma(u11, b, cmul(u10, a));
            }
        }
        #pragma unroll
        for (int t = 0; t < 32; ++t) P[d][t] = pack_c(B[t]);
    }
    // layer-3 k=0 (b-bit 11, wire 4): pairs cross containers -> packed
    {
        float2 u00 = LDC(4, 0), u01 = LDC(4, 1), u10 = LDC(4, 2), u11 = LDC(4, 3);
        #pragma unroll
        for (int mu = 0; mu < 2; ++mu)
        #pragma unroll
        for (int q = 0; q < 16; ++q) {
            const int h0 = 2 * q, h1 = 2 * q + 1;
            const int dA = mu, dB = mu ^ 1;           // dA = mu^(h0&1), h0 even
            const int rA = g5(h0), rB = g5(h1);
            float2 a = unpack_c(P[dA][rA]), b = unpack_c(P[dB][rB]);
            P[dA][rA] = pack_c(cfma(u01, b, cmul(u00, a)));
            P[dB][rB] = pack_c(cfma(u11, b, cmul(u10, a)));
        }
    }
    // layer-3 k=1..4: pairs stay within a physical container -> f32 per container
    #pragma unroll
    for (int d = 0; d < 2; ++d) {
        float2 B[32];
        #pragma unroll
        for (int t = 0; t < 32; ++t) B[t] = unpack_c(P[d][t]);
        #pragma unroll
        for (int k = 1; k < 5; ++k) {
            const int w = 4 - k, m = 1 << k;
            float2 u00 = LDC(w, 0), u01 = LDC(w, 1), u10 = LDC(w, 2), u11 = LDC(w, 3);
            #pragma unroll
            for (int q = 0; q < 16; ++q) {
                const int h0 = ((q >> k) << (k + 1)) | (q & (m - 1));
                const int h1 = h0 | m;
                const int rA = g5(h0), rB = g5(h1);   // both in this container
                float2 a = B[rA], b = B[rB];
                B[rA] = cfma(u01, b, cmul(u00, a));
                B[rB] = cfma(u11, b, cmul(u10, a));
            }
        }
        #pragma unroll
        for (int t = 0; t < 32; ++t) P[d][t] = pack_c(B[t]);
    }

    // ======== B->C exchange + Phase C (layer-3 low + final store), 2 halves ========
    #pragma unroll
    for (int step = 0; step < 2; ++step) {
        // write half: h in [step*16, step*16+16)  (ig5(h)<16 <=> h<16)
        #pragma unroll
        for (int hh = 0; hh < 16; ++hh) {
            const int h = (step << 4) | hh;
            const int sl = ig5(h) & 15;
            #pragma unroll
            for (int mu = 0; mu < 2; ++mu)
                ex[(sl << 11) | (mu << 10) | (tid ^ (mu ? 1023 : 0))] =
                    P[(mu ^ (h & 1)) & 1][g5(h)];
        }
        __syncthreads();
        const int v = wv | (step << 4);               // global slab; f_hi = v
        float2 A[32];
        #pragma unroll
        for (int r = 0; r < 32; ++r)
            A[r] = unpack_c(ex[((v & 15) << 11) | (r << 6) | lane]);
        apply11_T(A, sU, lane);                       // layer-3, wires 15..5
        uint32_t* sb = out + (((size_t)batch << 16) | (v << 11));
        const int cmask = (v & 1) ? 0x7FF : 0;        // parity(g5(v)) = v&1
        const int igl = ig6(lane);
        #pragma unroll
        for (int r = 0; r < 32; ++r) {
            const int addr = ((ig5(r) << 6) | (igl ^ ((__popc(r) & 1) ? 63 : 0))) ^ cmask;
            __builtin_nontemporal_store(pack_fin(A[r]), &sb[addr]);
        }
        __syncthreads();
    }
}

extern "C" void kernel_launch(void* const* d_in, const int* in_sizes, int n_in,
                              void* d_out, int out_size, void* d_ws, size_t ws_size,
                              hipStream_t stream) {
    const float* x   = (const float*)d_in[0];
    const float* par = (const float*)d_in[1];
    if (n_in >= 2 && in_sizes[0] < in_sizes[1]) {     // bind by size, order-proof
        x   = (const float*)d_in[1];
        par = (const float*)d_in[0];
    }
    uint32_t* out = (uint32_t*)d_out;                 // 256 x 65536 bf16-complex
    hipLaunchKernelGGL(k_fused, dim3(256), dim3(1024), 0, stream, x, par, out);
}

// Round 17
// 189.104 us; speedup vs baseline: 1.0025x; 1.0025x over previous
//
#include <hip/hip_runtime.h>
#include <stdint.h>

#define PI_F 3.14159265358979323846f

// complex helpers (float2 = {re, im})
__device__ __forceinline__ float2 cmul(float2 a, float2 b) {
    return make_float2(fmaf(a.x, b.x, -a.y * b.y),
                       fmaf(a.x, b.y,  a.y * b.x));
}
__device__ __forceinline__ float2 cfma(float2 a, float2 b, float2 c) { // a*b + c
    return make_float2(fmaf(a.x, b.x, fmaf(-a.y, b.y, c.x)),
                       fmaf(a.x, b.y, fmaf( a.y, b.x, c.y)));
}

// bf16 pair pack: low 16 = re, high 16 = im (RNE)
__device__ __forceinline__ uint32_t pack_c(float2 v) {
    uint32_t a = __float_as_uint(v.x), b = __float_as_uint(v.y);
    a = (a + 0x7FFFu + ((a >> 16) & 1u)) >> 16;
    b = (b + 0x7FFFu + ((b >> 16) & 1u)) >> 16;
    return a | (b << 16);
}
// FINAL output pack: low 16 = IM, high 16 = RE (validated output convention)
__device__ __forceinline__ uint32_t pack_fin(float2 v) {
    uint32_t a = __float_as_uint(v.x), b = __float_as_uint(v.y);
    a = (a + 0x7FFFu + ((a >> 16) & 1u)) >> 16;
    b = (b + 0x7FFFu + ((b >> 16) & 1u)) >> 16;
    return b | (a << 16);
}
__device__ __forceinline__ float2 unpack_c(uint32_t u) {
    return make_float2(__uint_as_float(u << 16), __uint_as_float(u & 0xFFFF0000u));
}

__device__ __forceinline__ int g5(int v)  { return (v ^ (v >> 1)) & 31; }
__device__ __forceinline__ int ig5(int v) { v ^= v >> 1; v ^= v >> 2; v ^= v >> 4; return v & 31; }
__device__ __forceinline__ int ig6(int v) { v ^= v >> 1; v ^= v >> 2; v ^= v >> 4; return v & 63; }

// gate-table access: sU[w*8 + (2*row+col)*2]
#define LDC(w, idx) make_float2(sU[(w)*8 + (idx)*2], sU[(w)*8 + (idx)*2 + 1])
#define FCOL(w, beta) make_float2(sU[(w)*8 + (beta)*4], sU[(w)*8 + (beta)*4 + 1])

// per-block gate table: U_w = RX(p1)·RZ(p0)·RY(pi*x_bw), 16 wires x 8 floats
__device__ __forceinline__ void build_table(float* sU, const float* __restrict__ x,
                                            const float* __restrict__ par, int batch, int tid) {
    if (tid < 16) {
        const int w = tid;
        float sy, cy, sz, cz, sx, cx;
        sincosf(0.5f * PI_F * x[batch * 16 + w], &sy, &cy);
        sincosf(0.5f * par[w * 2 + 0], &sz, &cz);
        sincosf(0.5f * par[w * 2 + 1], &sx, &cx);
        float ccc = cx * cy * cz, sss = sx * sy * sz;
        float ccs = cx * cy * sz, ssc = sx * sy * cz;
        float csc = cx * sy * cz, scs = sx * cy * sz;
        float css = cx * sy * sz, scc = sx * cy * cz;
        float* o = sU + w * 8;
        o[0] = ccc + sss;  o[1] = -(ccs + ssc);   // u00
        o[2] = scs - csc;  o[3] = css - scc;      // u01
        o[4] = csc - scs;  o[5] = css - scc;      // u10
        o[6] = ccc + sss;  o[7] = ccs + ssc;      // u11
    }
    __syncthreads();
}

// gates on slab bits 0..10, transposed ownership e = (r<<6)|lane.
// bits 0..5 = lane bits (shuffles, wires 15..10); bits 6..10 = register bits (wires 9..5)
__device__ __forceinline__ void apply11_T(float2 (&A)[32], const float* __restrict__ sU, int lane) {
    #pragma unroll
    for (int p = 0; p <= 5; ++p) {
        const int w = 15 - p;
        float2 u00 = LDC(w, 0), u01 = LDC(w, 1), u10 = LDC(w, 2), u11 = LDC(w, 3);
        const int myb = (lane >> p) & 1;
        float2 ca = myb ? u11 : u00;
        float2 cb = myb ? u10 : u01;
        #pragma unroll
        for (int r = 0; r < 32; ++r) {
            float px = __shfl_xor(A[r].x, 1 << p, 64);
            float py = __shfl_xor(A[r].y, 1 << p, 64);
            A[r] = cfma(cb, make_float2(px, py), cmul(ca, A[r]));
        }
    }
    #pragma unroll
    for (int k = 0; k <= 4; ++k) {                   // slab bit 6+k, wire 9-k
        const int w = 9 - k;
        float2 u00 = LDC(w, 0), u01 = LDC(w, 1), u10 = LDC(w, 2), u11 = LDC(w, 3);
        const int m = 1 << k;
        #pragma unroll
        for (int g = 0; g < 16; ++g) {
            int i = ((g >> k) << (k + 1)) | (g & (m - 1));
            int j = i | m;
            float2 a = A[i], b = A[j];
            A[i] = cfma(u01, b, cmul(u00, a));
            A[j] = cfma(u11, b, cmul(u10, a));
        }
    }
}

// ---- Phase A (one half): gen + layer-2 low gates, slab->LDS, LDS->P (STATIC indices)
template<int STEP>
__device__ __forceinline__ void phaseA(uint32_t (&P)[2][32], const float* __restrict__ sU,
                                       uint32_t* ex, int lane, int wv, int tid) {
    const int chunk = wv | (STEP << 4);           // slab = s bits 11..15
    const int gc = chunk ^ (chunk >> 1);
    float2 com = make_float2(1.f, 0.f);
    #pragma unroll
    for (int p = 11; p <= 15; ++p)
        com = cmul(com, FCOL(15 - p, (gc >> (p - 11)) & 1));
    #pragma unroll
    for (int p = 0; p <= 4; ++p)
        com = cmul(com, FCOL(15 - p, ((lane >> p) ^ (lane >> (p + 1))) & 1));
    const int l5 = (lane >> 5) & 1;
    const int c0 = chunk & 1;
    const float2 fa10 = FCOL(10, l5), fb10 = FCOL(10, l5 ^ 1);   // p=5:  l5 ^ r0
    const float2 fa9  = FCOL(9, 0),   fb9  = FCOL(9, 1);         // p=6:  r0 ^ r1
    const float2 fa8  = FCOL(8, 0),   fb8  = FCOL(8, 1);         // p=7:  r1 ^ r2
    const float2 fa7  = FCOL(7, 0),   fb7  = FCOL(7, 1);         // p=8:  r2 ^ r3
    const float2 fa6  = FCOL(6, 0),   fb6  = FCOL(6, 1);         // p=9:  r3 ^ r4
    const float2 fa5  = FCOL(5, c0),  fb5  = FCOL(5, c0 ^ 1);    // p=10: r4 ^ c0
    float2 A[32];
    #pragma unroll
    for (int r = 0; r < 32; ++r) {
        float2 v = com;
        v = cmul(v, ((r & 1) != 0)                     ? fb10 : fa10);
        v = cmul(v, ((((r >> 0) ^ (r >> 1)) & 1) != 0) ? fb9 : fa9);
        v = cmul(v, ((((r >> 1) ^ (r >> 2)) & 1) != 0) ? fb8 : fa8);
        v = cmul(v, ((((r >> 2) ^ (r >> 3)) & 1) != 0) ? fb7 : fa7);
        v = cmul(v, ((((r >> 3) ^ (r >> 4)) & 1) != 0) ? fb6 : fa6);
        v = cmul(v, (((r >> 4) & 1) != 0)              ? fb5 : fa5);
        A[r] = v;
    }
    apply11_T(A, sU, lane);                        // layer-2, wires 15..5
    {   // write slab to LDS at ig11-permuted position (validated store map)
        uint32_t* lb = ex + ((chunk & 15) << 11);
        const int igl = ig6(lane);
        #pragma unroll
        for (int r = 0; r < 32; ++r)
            lb[(ig5(r) << 6) | (igl ^ ((__popc(r) & 1) ? 63 : 0))] = pack_c(A[r]);
    }
    __syncthreads();
    // read phase-B share for t in this half (validated p2 read map, y = tid)
    #pragma unroll
    for (int tt = 0; tt < 16; ++tt) {
        #pragma unroll
        for (int d = 0; d < 2; ++d)
            P[d][(STEP << 4) | tt] =               // compile-time index
                ex[(tt << 11) | (d << 10) | (tid ^ (d ? 1023 : 0))];
    }
    __syncthreads();
}

// ---- Phase C (one half): P->LDS, layer-3 low gates, final store (STATIC indices)
template<int STEP>
__device__ __forceinline__ void phaseC(uint32_t (&P)[2][32], const float* __restrict__ sU,
                                       uint32_t* ex, int lane, int wv, int tid,
                                       int batch, uint32_t* __restrict__ out) {
    #pragma unroll
    for (int hh = 0; hh < 16; ++hh) {
        const int h = (STEP << 4) | hh;            // compile-time
        const int sl = ig5(h) & 15;
        #pragma unroll
        for (int mu = 0; mu < 2; ++mu)
            ex[(sl << 11) | (mu << 10) | (tid ^ (mu ? 1023 : 0))] =
                P[(mu ^ (h & 1)) & 1][g5(h)];      // compile-time indices
    }
    __syncthreads();
    const int v = wv | (STEP << 4);                // global slab; f_hi = v
    float2 A[32];
    #pragma unroll
    for (int r = 0; r < 32; ++r)
        A[r] = unpack_c(ex[((v & 15) << 11) | (r << 6) | lane]);
    apply11_T(A, sU, lane);                        // layer-3, wires 15..5
    uint32_t* sb = out + (((size_t)batch << 16) | (v << 11));
    const int cmask = (v & 1) ? 0x7FF : 0;         // parity(g5(v)) = v&1
    const int igl = ig6(lane);
    #pragma unroll
    for (int r = 0; r < 32; ++r) {
        const int addr = ((ig5(r) << 6) | (igl ^ ((__popc(r) & 1) ? 63 : 0))) ^ cmask;
        __builtin_nontemporal_store(pack_fin(A[r]), &sb[addr]);
    }
    __syncthreads();
}

// ---- Fused kernel: one block (1024 thr) = one batch; state in registers; LDS re-chunk.
// LDS (128KB) caps residency at 1 block/CU = 4 waves/EU. Pure attributes (no __launch_bounds__,
// which overrode amdgpu_waves_per_eu in R16): pin waves/EU to 4 -> VGPR budget 512/4 = 128.
__global__ __attribute__((amdgpu_flat_work_group_size(1024, 1024), amdgpu_waves_per_eu(4, 4)))
void k_fused(const float* __restrict__ x,
             const float* __restrict__ par,
             uint32_t* __restrict__ out) {
    __shared__ float sU[128];
    __shared__ uint32_t ex[32768];     // 128 KB staging: 16 slabs x 2048
    const int tid = threadIdx.x, lane = tid & 63, wv = tid >> 6;   // 16 waves
    const int batch = blockIdx.x;
    build_table(sU, x, par, batch, tid);

    uint32_t P[2][32];   // phase-B state: P[d][t], bf16-packed

    // ======== Phase A (gen + layer-2 low gates) + A->B exchange, 2 halves ========
    phaseA<0>(P, sU, ex, lane, wv, tid);
    phaseA<1>(P, sU, ex, lane, wv, tid);

    // ======== Phase B: layer-2 high, CNOT relabel, layer-3 high ========
    // layer-2 (s-bits 11..15): d-containers independent -> f32 per container
    #pragma unroll
    for (int d = 0; d < 2; ++d) {
        float2 B[32];
        #pragma unroll
        for (int t = 0; t < 32; ++t) B[t] = unpack_c(P[d][t]);
        #pragma unroll
        for (int j = 0; j < 5; ++j) {
            const int w = 4 - j, m = 1 << j;
            float2 u00 = LDC(w, 0), u01 = LDC(w, 1), u10 = LDC(w, 2), u11 = LDC(w, 3);
            #pragma unroll
            for (int g = 0; g < 16; ++g) {
                const int t0 = ((g >> j) << (j + 1)) | (g & (m - 1));
                const int t1 = t0 | m;
                float2 a = B[t0], b = B[t1];
                B[t0] = cfma(u01, b, cmul(u00, a));
                B[t1] = cfma(u11, b, cmul(u10, a));
            }
        }
        #pragma unroll
        for (int t = 0; t < 32; ++t) P[d][t] = pack_c(B[t]);
    }
    // layer-3 k=0 (b-bit 11, wire 4): pairs cross containers -> packed
    {
        float2 u00 = LDC(4, 0), u01 = LDC(4, 1), u10 = LDC(4, 2), u11 = LDC(4, 3);
        #pragma unroll
        for (int mu = 0; mu < 2; ++mu)
        #pragma unroll
        for (int q = 0; q < 16; ++q) {
            const int h0 = 2 * q, h1 = 2 * q + 1;
            const int dA = mu, dB = mu ^ 1;           // dA = mu^(h0&1), h0 even
            const int rA = g5(h0), rB = g5(h1);
            float2 a = unpack_c(P[dA][rA]), b = unpack_c(P[dB][rB]);
            P[dA][rA] = pack_c(cfma(u01, b, cmul(u00, a)));
            P[dB][rB] = pack_c(cfma(u11, b, cmul(u10, a)));
        }
    }
    // layer-3 k=1..4: pairs stay within a physical container -> f32 per container
    #pragma unroll
    for (int d = 0; d < 2; ++d) {
        float2 B[32];
        #pragma unroll
        for (int t = 0; t < 32; ++t) B[t] = unpack_c(P[d][t]);
        #pragma unroll
        for (int k = 1; k < 5; ++k) {
            const int w = 4 - k, m = 1 << k;
            float2 u00 = LDC(w, 0), u01 = LDC(w, 1), u10 = LDC(w, 2), u11 = LDC(w, 3);
            #pragma unroll
            for (int q = 0; q < 16; ++q) {
                const int h0 = ((q >> k) << (k + 1)) | (q & (m - 1));
                const int h1 = h0 | m;
                const int rA = g5(h0), rB = g5(h1);   // both in this container
                float2 a = B[rA], b = B[rB];
                B[rA] = cfma(u01, b, cmul(u00, a));
                B[rB] = cfma(u11, b, cmul(u10, a));
            }
        }
        #pragma unroll
        for (int t = 0; t < 32; ++t) P[d][t] = pack_c(B[t]);
    }

    // ======== B->C exchange + Phase C (layer-3 low + final store), 2 halves ========
    phaseC<0>(P, sU, ex, lane, wv, tid, batch, out);
    phaseC<1>(P, sU, ex, lane, wv, tid, batch, out);
}

extern "C" void kernel_launch(void* const* d_in, const int* in_sizes, int n_in,
                              void* d_out, int out_size, void* d_ws, size_t ws_size,
                              hipStream_t stream) {
    const float* x   = (const float*)d_in[0];
    const float* par = (const float*)d_in[1];
    if (n_in >= 2 && in_sizes[0] < in_sizes[1]) {     // bind by size, order-proof
        x   = (const float*)d_in[1];
        par = (const float*)d_in[0];
    }
    uint32_t* out = (uint32_t*)d_out;                 // 256 x 65536 bf16-complex
    hipLaunchKernelGGL(k_fused, dim3(256), dim3(1024), 0, stream, x, par, out);
}